// Round 6
// baseline (522.398 us; speedup 1.0000x reference)
//
#include <hip/hip_runtime.h>
#include <stdint.h>

typedef __attribute__((ext_vector_type(8))) short bf16x8;   // 8 bf16 = 4 VGPR (MFMA A/B frag)
typedef __attribute__((ext_vector_type(4))) float f32x4;    // MFMA C/D frag
typedef __attribute__((ext_vector_type(4))) unsigned short us4;

__device__ __forceinline__ unsigned short f2bf(float f) {   // RNE f32 -> bf16
  union { float f; unsigned u; } x; x.f = f;
  unsigned r = x.u + 0x7FFFu + ((x.u >> 16) & 1u);
  return (unsigned short)(r >> 16);
}
__device__ __forceinline__ float bf2f(unsigned short h) {
  union { unsigned u; float f; } x; x.u = ((unsigned)h) << 16;
  return x.f;
}

// async global->LDS, 16B per lane; LDS dest is wave-uniform base + lane*16
#define GL2LDS(g, l) __builtin_amdgcn_global_load_lds( \
    (const __attribute__((address_space(1))) unsigned int*)(g), \
    (__attribute__((address_space(3))) unsigned int*)(l), 16, 0, 0)

// ---------------- f32 -> bf16 weight conversion ----------------
__global__ __launch_bounds__(256)
void cvt_f32_bf16(const float* __restrict__ in, unsigned short* __restrict__ out, int n4)
{
  const int i = blockIdx.x * 256 + threadIdx.x;
  if (i < n4) {
    const float4 f = ((const float4*)in)[i];
    us4 v;
    v[0] = f2bf(f.x); v[1] = f2bf(f.y); v[2] = f2bf(f.z); v[3] = f2bf(f.w);
    ((us4*)out)[i] = v;
  }
}

// out_proj: f32 [1024,1024] -> bf16 transposed (final GEMM needs W[n][k] = out_proj^T)
__global__ __launch_bounds__(256)
void transpose_cvt(const float* __restrict__ in, unsigned short* __restrict__ out)
{
  __shared__ float t[32][33];
  const int bx = blockIdx.x * 32, by = blockIdx.y * 32;
  const int tx = threadIdx.x & 31, ty = threadIdx.x >> 5;
#pragma unroll
  for (int i = 0; i < 32; i += 8)
    t[ty + i][tx] = in[(size_t)(by + ty + i) * 1024 + bx + tx];
  __syncthreads();
#pragma unroll
  for (int i = 0; i < 32; i += 8)
    out[(size_t)(bx + ty + i) * 1024 + by + tx] = f2bf(t[tx][ty + i]);
}

// ---------------- GEMM: C[M,N] = A[M,K] @ W[N,K]^T ----------------
// A is f32 (AF32=true, converted in-register) or bf16; W bf16.
// tile 128x128, BK=32, 256 threads = 4 waves 2x2, each wave 4x4 of 16x16x32 MFMA.
// MODE 0: C bf16 row-major (ldc)
// MODE 1: C f32 row-major (ldc)     <-- final output (d_out is FLOAT32; proven round 5)
// MODE 2: V^T store: C[b][n][s] bf16, b=row>>11, s=row&2047 (S=2048, d=1024 hard-coded)
// CAUSAL: skip blocks entirely above the diagonal
// PVLIM:  limit K loop to m0+128 (P has zeros above diagonal)
template<bool AF32, int MODE, bool CAUSAL, bool PVLIM>
__global__ __launch_bounds__(256, 2)
void gemm_bt(const void* __restrict__ Av, const unsigned short* __restrict__ W,
             void* __restrict__ Cv, int lda, int ldw, int ldc, int K)
{
  const int m0 = blockIdx.y * 128;
  const int n0 = blockIdx.x * 128;
  if (CAUSAL && n0 > m0 + 127) return;

  const int tid  = threadIdx.x;
  const int lane = tid & 63;
  const int wave = tid >> 6;
  const int quad = lane >> 4;
  const int l16  = lane & 15;
  const int wm   = wave & 1;
  const int wn   = wave >> 1;

  __shared__ char lds[AF32 ? (16384 + 8192) : (8192 + 8192)];
  char* ldsA = lds;
  char* ldsW = lds + (AF32 ? 16384 : 8192);

  const int wrow = tid >> 2;            // 0..63, W-tile row of this thread's 16B chunk
  const unsigned short* Wb = W + (size_t)n0 * ldw + (tid & 3) * 8;

  f32x4 acc[4][4] = {};
  const int Keff = PVLIM ? ((m0 + 128 < K) ? (m0 + 128) : K) : K;

  for (int k0 = 0; k0 < Keff; k0 += 32) {
    __syncthreads();                                   // all waves done reading LDS
    if (AF32) {
      const float* A = (const float*)Av + (size_t)m0 * lda + k0;
      // 128 rows x 32 f32 = 1024 chunks of 16B; chunk c: row c>>3, 4 floats at (c&7)*4
#pragma unroll
      for (int t = 0; t < 4; ++t) {
        const int c = tid + t * 256;
        GL2LDS(A + (size_t)(c >> 3) * lda + (c & 7) * 4, ldsA + c * 16);
      }
    } else {
      const unsigned short* A = (const unsigned short*)Av + (size_t)m0 * lda + k0 + (tid & 3) * 8;
      GL2LDS(A + (size_t)wrow        * lda, ldsA +        tid * 16);
      GL2LDS(A + (size_t)(wrow + 64) * lda, ldsA + 4096 + tid * 16);
    }
    GL2LDS(Wb + (size_t)wrow        * ldw + k0, ldsW +        tid * 16);
    GL2LDS(Wb + (size_t)(wrow + 64) * ldw + k0, ldsW + 4096 + tid * 16);
    __syncthreads();                                   // vmcnt(0) drained before barrier

    bf16x8 af[4], wf[4];
#pragma unroll
    for (int mt = 0; mt < 4; ++mt) {
      const int row = wm * 64 + mt * 16 + l16;
      if (AF32) {
        const float* src = (const float*)ldsA + row * 32 + quad * 8;
        bf16x8 v;
#pragma unroll
        for (int j = 0; j < 8; ++j) v[j] = (short)f2bf(src[j]);
        af[mt] = v;
      } else {
        af[mt] = *(const bf16x8*)(ldsA + (row * 32 + quad * 8) * 2);
      }
    }
#pragma unroll
    for (int nt = 0; nt < 4; ++nt)
      wf[nt] = *(const bf16x8*)(ldsW + ((wn * 64 + nt * 16 + l16) * 32 + quad * 8) * 2);
#pragma unroll
    for (int mt = 0; mt < 4; ++mt)
#pragma unroll
      for (int nt = 0; nt < 4; ++nt)
        acc[mt][nt] = __builtin_amdgcn_mfma_f32_16x16x32_bf16(af[mt], wf[nt], acc[mt][nt], 0, 0, 0);
  }

  // epilogue: D mapping col = lane&15, row = quad*4 + reg  [verified m89/m91]
#pragma unroll
  for (int mt = 0; mt < 4; ++mt) {
#pragma unroll
    for (int nt = 0; nt < 4; ++nt) {
      const int gr = m0 + wm * 64 + mt * 16 + quad * 4;
      const int gc = n0 + wn * 64 + nt * 16 + l16;
      if (MODE == 2) {
        us4 v;
#pragma unroll
        for (int r = 0; r < 4; ++r) v[r] = f2bf(acc[mt][nt][r]);
        const int b = gr >> 11, s = gr & 2047;
        *(us4*)((unsigned short*)Cv + (size_t)b * (1024 * 2048) + (size_t)gc * 2048 + s) = v;
      } else if (MODE == 1) {
#pragma unroll
        for (int r = 0; r < 4; ++r)
          ((float*)Cv)[(size_t)(gr + r) * ldc + gc] = acc[mt][nt][r];
      } else {
#pragma unroll
        for (int r = 0; r < 4; ++r)
          ((unsigned short*)Cv)[(size_t)(gr + r) * ldc + gc] = f2bf(acc[mt][nt][r]);
      }
    }
  }
}

// causal softmax over one row of the (per-batch) bf16 score matrix, in place.
// row r = blockIdx.x; valid cols [0, r]; scale 1/sqrt(1024)=1/32 applied pre-exp.
__global__ __launch_bounds__(256)
void softmax_causal(unsigned short* __restrict__ SP)
{
  const int r   = blockIdx.x;
  const int tid = threadIdx.x;
  unsigned short* row = SP + (size_t)r * 2048;
  const int n = r + 1;

  float vals[8];
  float lmax = -1e30f;
#pragma unroll
  for (int i = 0; i < 8; ++i) {
    const int c = tid + i * 256;
    const float f = bf2f(row[c]);   // beyond n: finite garbage, masked below
    vals[i] = f;
    if (c < n) lmax = fmaxf(lmax, f);
  }
#pragma unroll
  for (int m = 32; m; m >>= 1) lmax = fmaxf(lmax, __shfl_xor(lmax, m, 64));
  __shared__ float redm[4], reds[4];
  if ((tid & 63) == 0) redm[tid >> 6] = lmax;
  __syncthreads();
  lmax = fmaxf(fmaxf(redm[0], redm[1]), fmaxf(redm[2], redm[3]));

  float e[8];
  float lsum = 0.f;
#pragma unroll
  for (int i = 0; i < 8; ++i) {
    const int c = tid + i * 256;
    const float ev = (c < n) ? __expf((vals[i] - lmax) * 0.03125f) : 0.f;
    e[i] = ev;
    lsum += ev;
  }
#pragma unroll
  for (int m = 32; m; m >>= 1) lsum += __shfl_xor(lsum, m, 64);
  if ((tid & 63) == 0) reds[tid >> 6] = lsum;
  __syncthreads();
  lsum = reds[0] + reds[1] + reds[2] + reds[3];
  const float inv = 1.f / lsum;
#pragma unroll
  for (int i = 0; i < 8; ++i)
    row[tid + i * 256] = f2bf(e[i] * inv);   // zeros beyond the diagonal
}

extern "C" void kernel_launch(void* const* d_in, const int* in_sizes, int n_in,
                              void* d_out, int out_size, void* d_ws, size_t ws_size,
                              hipStream_t stream)
{
  (void)in_sizes; (void)n_in; (void)out_size; (void)ws_size;
  // setup_inputs dict order: k, q, v, out_proj, x — f32 inputs, f32 OUTPUT (proven round 5)
  const float* wk_f = (const float*)d_in[0];
  const float* wq_f = (const float*)d_in[1];
  const float* wv_f = (const float*)d_in[2];
  const float* wo_f = (const float*)d_in[3];
  const float* x_f  = (const float*)d_in[4];
  float* out = (float*)d_out;

  // workspace: 58 MiB with aliasing
  char* p = (char*)d_ws;
  unsigned short* QO  = (unsigned short*)(p);                       // [0,16M): Q, then O per batch
  unsigned short* Km  = (unsigned short*)(p + ((size_t)16 << 20));  // [16,32M)
  unsigned short* VT  = (unsigned short*)(p + ((size_t)32 << 20));  // [32,48M): [B][d][S]
  unsigned short* SP  = (unsigned short*)(p + ((size_t)48 << 20));  // [48,56M): one batch scores/P
  unsigned short* wqb = (unsigned short*)(p + ((size_t)48 << 20));  // aliased into SP (dead before scores)
  unsigned short* wkb = (unsigned short*)(p + ((size_t)50 << 20));
  unsigned short* wvb = (unsigned short*)(p + ((size_t)52 << 20));
  unsigned short* opT = (unsigned short*)(p + ((size_t)56 << 20));  // [56,58M)

  dim3 blk(256);

  // weight conversions (1024x1024 each)
  cvt_f32_bf16<<<dim3(1024), blk, 0, stream>>>(wq_f, wqb, 1024 * 1024 / 4);
  cvt_f32_bf16<<<dim3(1024), blk, 0, stream>>>(wk_f, wkb, 1024 * 1024 / 4);
  cvt_f32_bf16<<<dim3(1024), blk, 0, stream>>>(wv_f, wvb, 1024 * 1024 / 4);
  transpose_cvt<<<dim3(32, 32), blk, 0, stream>>>(wo_f, opT);

  // projections: A = x (f32, staged+converted in kernel), M=8192, N=1024, K=1024
  gemm_bt<true,0,false,false><<<dim3(8, 64), blk, 0, stream>>>(x_f, wqb, QO, 1024, 1024, 1024, 1024);
  gemm_bt<true,0,false,false><<<dim3(8, 64), blk, 0, stream>>>(x_f, wkb, Km, 1024, 1024, 1024, 1024);
  gemm_bt<true,2,false,false><<<dim3(8, 64), blk, 0, stream>>>(x_f, wvb, VT, 1024, 1024, 0,    1024);

  // attention per batch (SP reused; O overwrites Q[z] after scores_z consumed it)
  for (int z = 0; z < 4; ++z) {
    unsigned short* Qz = QO + (size_t)z * 2048 * 1024;
    unsigned short* Kz = Km + (size_t)z * 2048 * 1024;
    unsigned short* Vz = VT + (size_t)z * 1024 * 2048;
    gemm_bt<false,0,true,false><<<dim3(16, 16), blk, 0, stream>>>(Qz, Kz, SP, 1024, 1024, 2048, 1024);
    softmax_causal<<<dim3(2048), blk, 0, stream>>>(SP);
    gemm_bt<false,0,false,true><<<dim3(8, 16), blk, 0, stream>>>(SP, Vz, Qz, 2048, 2048, 1024, 2048);
  }

  // out = O @ out_proj, f32 store into d_out (M=8192, N=1024, K=1024)
  gemm_bt<false,1,false,false><<<dim3(8, 64), blk, 0, stream>>>(QO, opT, out, 1024, 1024, 1024, 1024);
}

// Round 7
// 297.086 us; speedup vs baseline: 1.7584x; 1.7584x over previous
//
#include <hip/hip_runtime.h>
#include <stdint.h>

typedef __attribute__((ext_vector_type(8))) short bf16x8;   // 8 bf16 = 4 VGPR (MFMA A/B frag)
typedef __attribute__((ext_vector_type(4))) float f32x4;    // MFMA C/D frag
typedef __attribute__((ext_vector_type(4))) unsigned short us4;

__device__ __forceinline__ unsigned short f2bf(float f) {   // RNE f32 -> bf16
  union { float f; unsigned u; } x; x.f = f;
  unsigned r = x.u + 0x7FFFu + ((x.u >> 16) & 1u);
  return (unsigned short)(r >> 16);
}
__device__ __forceinline__ float bf2f(unsigned short h) {
  union { unsigned u; float f; } x; x.u = ((unsigned)h) << 16;
  return x.f;
}

// async global->LDS, 16B per lane; LDS dest is wave-uniform base + lane*16
#define GL2LDS(g, l) __builtin_amdgcn_global_load_lds( \
    (const __attribute__((address_space(1))) unsigned int*)(g), \
    (__attribute__((address_space(3))) unsigned int*)(l), 16, 0, 0)

// ---------------- x: f32 -> bf16 (vectorized) ----------------
__global__ __launch_bounds__(256)
void cvt_x(const float* __restrict__ in, unsigned short* __restrict__ out)
{
  const int i = blockIdx.x * 256 + threadIdx.x;   // grid 8192 covers 8192*1024 elems /4
  const float4 f = ((const float4*)in)[i];
  us4 v;
  v[0] = f2bf(f.x); v[1] = f2bf(f.y); v[2] = f2bf(f.z); v[3] = f2bf(f.w);
  ((us4*)out)[i] = v;
}

// ---------------- fused weight prep ----------------
// z=0,1,2: convert wq/wk/wv f32->bf16 (grid.x=1024)
// z=3:     transpose+convert out_proj (grid.x=1024 as 32x32 tiles)
__global__ __launch_bounds__(256)
void weight_prep(const float* __restrict__ wq, const float* __restrict__ wk,
                 const float* __restrict__ wv, const float* __restrict__ wo,
                 unsigned short* __restrict__ wqb, unsigned short* __restrict__ wkb,
                 unsigned short* __restrict__ wvb, unsigned short* __restrict__ opT)
{
  __shared__ float t[32][33];
  const int z = blockIdx.z;
  if (z < 3) {
    const float* in = (z == 0) ? wq : (z == 1) ? wk : wv;
    unsigned short* out = (z == 0) ? wqb : (z == 1) ? wkb : wvb;
    const int i = blockIdx.x * 256 + threadIdx.x;
    const float4 f = ((const float4*)in)[i];
    us4 v;
    v[0] = f2bf(f.x); v[1] = f2bf(f.y); v[2] = f2bf(f.z); v[3] = f2bf(f.w);
    ((us4*)out)[i] = v;
  } else {
    const int bx = (blockIdx.x & 31) * 32, by = (blockIdx.x >> 5) * 32;
    const int tx = threadIdx.x & 31, ty = threadIdx.x >> 5;
#pragma unroll
    for (int i = 0; i < 32; i += 8)
      t[ty + i][tx] = wo[(size_t)(by + ty + i) * 1024 + bx + tx];
    __syncthreads();
#pragma unroll
    for (int i = 0; i < 32; i += 8)
      opT[(size_t)(bx + ty + i) * 1024 + by + tx] = f2bf(t[tx][ty + i]);
  }
}

// ---------------- fused QKV projection ----------------
// xb[8192,1024] bf16; blockIdx.x in [0,24): weight = x>>3, n0 = (x&7)*128.
// Q,K row-major [8192,1024]; V stored transposed VT[b][d][s] (b=row>>11,s=row&2047).
__global__ __launch_bounds__(256, 2)
void gemm_qkv(const unsigned short* __restrict__ xb,
              const unsigned short* __restrict__ wq, const unsigned short* __restrict__ wk,
              const unsigned short* __restrict__ wv,
              unsigned short* __restrict__ Q, unsigned short* __restrict__ Kb,
              unsigned short* __restrict__ VT)
{
  const int m0 = blockIdx.y * 128;
  const int wsel = blockIdx.x >> 3;
  const int n0 = (blockIdx.x & 7) * 128;
  const unsigned short* W = (wsel == 0) ? wq : (wsel == 1) ? wk : wv;

  const int tid = threadIdx.x;
  const int lane = tid & 63, wave = tid >> 6;
  const int quad = lane >> 4, l16 = lane & 15;
  const int wm = wave & 1, wn = wave >> 1;

  __shared__ unsigned short As[128 * 32], Ws[128 * 32];
  char* ldsA = (char*)As; char* ldsW = (char*)Ws;
  const int wrow = tid >> 2;
  const unsigned short* Ab = xb + (size_t)m0 * 1024 + (tid & 3) * 8;
  const unsigned short* Wb = W  + (size_t)n0 * 1024 + (tid & 3) * 8;

  f32x4 acc[4][4] = {};
  for (int k0 = 0; k0 < 1024; k0 += 32) {
    __syncthreads();
    GL2LDS(Ab + (size_t)wrow * 1024 + k0,        ldsA +        tid * 16);
    GL2LDS(Ab + (size_t)(wrow + 64) * 1024 + k0, ldsA + 4096 + tid * 16);
    GL2LDS(Wb + (size_t)wrow * 1024 + k0,        ldsW +        tid * 16);
    GL2LDS(Wb + (size_t)(wrow + 64) * 1024 + k0, ldsW + 4096 + tid * 16);
    __syncthreads();
    bf16x8 af[4], wf[4];
#pragma unroll
    for (int mt = 0; mt < 4; ++mt)
      af[mt] = *(const bf16x8*)(ldsA + ((wm * 64 + mt * 16 + l16) * 32 + quad * 8) * 2);
#pragma unroll
    for (int nt = 0; nt < 4; ++nt)
      wf[nt] = *(const bf16x8*)(ldsW + ((wn * 64 + nt * 16 + l16) * 32 + quad * 8) * 2);
#pragma unroll
    for (int mt = 0; mt < 4; ++mt)
#pragma unroll
      for (int nt = 0; nt < 4; ++nt)
        acc[mt][nt] = __builtin_amdgcn_mfma_f32_16x16x32_bf16(af[mt], wf[nt], acc[mt][nt], 0, 0, 0);
  }

#pragma unroll
  for (int mt = 0; mt < 4; ++mt) {
#pragma unroll
    for (int nt = 0; nt < 4; ++nt) {
      const int gr = m0 + wm * 64 + mt * 16 + quad * 4;
      const int gc = n0 + wn * 64 + nt * 16 + l16;
      if (wsel == 2) {
        us4 v;
#pragma unroll
        for (int r = 0; r < 4; ++r) v[r] = f2bf(acc[mt][nt][r]);
        const int b = gr >> 11, s = gr & 2047;
        *(us4*)(VT + (size_t)b * (1024 * 2048) + (size_t)gc * 2048 + s) = v;
      } else {
        unsigned short* C = (wsel == 0) ? Q : Kb;
#pragma unroll
        for (int r = 0; r < 4; ++r)
          C[(size_t)(gr + r) * 1024 + gc] = f2bf(acc[mt][nt][r]);
      }
    }
  }
}

// ---------------- generic bf16 GEMM: C = A @ W^T ----------------
// MODE 0: C bf16; MODE 1: C f32 (d_out). CAUSAL: block skip. PVLIM: Keff = m0+128.
// z strides in elements.
template<int MODE, bool CAUSAL, bool PVLIM>
__global__ __launch_bounds__(256, 2)
void gemm_bt(const unsigned short* __restrict__ A, const unsigned short* __restrict__ W,
             void* __restrict__ Cv, int lda, int ldw, int ldc, int K,
             long long sAz, long long sWz, long long sCz)
{
  const int m0 = blockIdx.y * 128;
  const int n0 = blockIdx.x * 128;
  if (CAUSAL && n0 > m0 + 127) return;
  const int z = blockIdx.z;
  A += (size_t)z * sAz;
  W += (size_t)z * sWz;

  const int tid = threadIdx.x;
  const int lane = tid & 63, wave = tid >> 6;
  const int quad = lane >> 4, l16 = lane & 15;
  const int wm = wave & 1, wn = wave >> 1;

  __shared__ unsigned short As[128 * 32], Ws[128 * 32];
  char* ldsA = (char*)As; char* ldsW = (char*)Ws;
  const int wrow = tid >> 2;
  const unsigned short* Ab = A + (size_t)m0 * lda + (tid & 3) * 8;
  const unsigned short* Wb = W + (size_t)n0 * ldw + (tid & 3) * 8;

  f32x4 acc[4][4] = {};
  const int Keff = PVLIM ? ((m0 + 128 < K) ? (m0 + 128) : K) : K;

  for (int k0 = 0; k0 < Keff; k0 += 32) {
    __syncthreads();
    GL2LDS(Ab + (size_t)wrow * lda + k0,        ldsA +        tid * 16);
    GL2LDS(Ab + (size_t)(wrow + 64) * lda + k0, ldsA + 4096 + tid * 16);
    GL2LDS(Wb + (size_t)wrow * ldw + k0,        ldsW +        tid * 16);
    GL2LDS(Wb + (size_t)(wrow + 64) * ldw + k0, ldsW + 4096 + tid * 16);
    __syncthreads();
    bf16x8 af[4], wf[4];
#pragma unroll
    for (int mt = 0; mt < 4; ++mt)
      af[mt] = *(const bf16x8*)(ldsA + ((wm * 64 + mt * 16 + l16) * 32 + quad * 8) * 2);
#pragma unroll
    for (int nt = 0; nt < 4; ++nt)
      wf[nt] = *(const bf16x8*)(ldsW + ((wn * 64 + nt * 16 + l16) * 32 + quad * 8) * 2);
#pragma unroll
    for (int mt = 0; mt < 4; ++mt)
#pragma unroll
      for (int nt = 0; nt < 4; ++nt)
        acc[mt][nt] = __builtin_amdgcn_mfma_f32_16x16x32_bf16(af[mt], wf[nt], acc[mt][nt], 0, 0, 0);
  }

#pragma unroll
  for (int mt = 0; mt < 4; ++mt) {
#pragma unroll
    for (int nt = 0; nt < 4; ++nt) {
      const int gr = m0 + wm * 64 + mt * 16 + quad * 4;
      const int gc = n0 + wn * 64 + nt * 16 + l16;
      if (MODE == 1) {
        float* C = (float*)Cv + (size_t)z * sCz;
#pragma unroll
        for (int r = 0; r < 4; ++r)
          C[(size_t)(gr + r) * ldc + gc] = acc[mt][nt][r];
      } else {
        unsigned short* C = (unsigned short*)Cv + (size_t)z * sCz;
#pragma unroll
        for (int r = 0; r < 4; ++r)
          C[(size_t)(gr + r) * ldc + gc] = f2bf(acc[mt][nt][r]);
      }
    }
  }
}

// causal softmax; blockIdx.x = b*2048 + r; valid cols [0,r]; scale 1/32 pre-exp.
__global__ __launch_bounds__(256)
void softmax_causal(unsigned short* __restrict__ SP)
{
  const int gid = blockIdx.x;
  const int r   = gid & 2047;
  const int tid = threadIdx.x;
  unsigned short* row = SP + (size_t)gid * 2048;
  const int n = r + 1;

  float vals[8];
  float lmax = -1e30f;
#pragma unroll
  for (int i = 0; i < 8; ++i) {
    const int c = tid + i * 256;
    const float f = bf2f(row[c]);   // beyond n: finite garbage, masked below
    vals[i] = f;
    if (c < n) lmax = fmaxf(lmax, f);
  }
#pragma unroll
  for (int m = 32; m; m >>= 1) lmax = fmaxf(lmax, __shfl_xor(lmax, m, 64));
  __shared__ float redm[4], reds[4];
  if ((tid & 63) == 0) redm[tid >> 6] = lmax;
  __syncthreads();
  lmax = fmaxf(fmaxf(redm[0], redm[1]), fmaxf(redm[2], redm[3]));

  float e[8];
  float lsum = 0.f;
#pragma unroll
  for (int i = 0; i < 8; ++i) {
    const int c = tid + i * 256;
    const float ev = (c < n) ? __expf((vals[i] - lmax) * 0.03125f) : 0.f;
    e[i] = ev;
    lsum += ev;
  }
#pragma unroll
  for (int m = 32; m; m >>= 1) lsum += __shfl_xor(lsum, m, 64);
  if ((tid & 63) == 0) reds[tid >> 6] = lsum;
  __syncthreads();
  lsum = reds[0] + reds[1] + reds[2] + reds[3];
  const float inv = 1.f / lsum;
#pragma unroll
  for (int i = 0; i < 8; ++i)
    row[tid + i * 256] = f2bf(e[i] * inv);   // zeros beyond the diagonal
}

extern "C" void kernel_launch(void* const* d_in, const int* in_sizes, int n_in,
                              void* d_out, int out_size, void* d_ws, size_t ws_size,
                              hipStream_t stream)
{
  (void)in_sizes; (void)n_in; (void)out_size; (void)ws_size;
  // dict order: k, q, v, out_proj, x — f32 inputs, f32 output
  const float* wk_f = (const float*)d_in[0];
  const float* wq_f = (const float*)d_in[1];
  const float* wv_f = (const float*)d_in[2];
  const float* wo_f = (const float*)d_in[3];
  const float* x_f  = (const float*)d_in[4];
  float* out = (float*)d_out;

  // ws layout (98 MiB):
  char* p = (char*)d_ws;
  unsigned short* xb  = (unsigned short*)(p);                       // [0,16M)
  unsigned short* QO  = (unsigned short*)(p + ((size_t)16 << 20));  // [16,32M): Q, then O
  unsigned short* Kb  = (unsigned short*)(p + ((size_t)32 << 20));  // [32,48M)
  unsigned short* VT  = (unsigned short*)(p + ((size_t)48 << 20));  // [48,64M): [B][d][S]
  unsigned short* SP  = (unsigned short*)(p + ((size_t)64 << 20));  // [64,96M): [B][S][S]
  unsigned short* wqb = (unsigned short*)(p + ((size_t)64 << 20));  // alias (dead before scores)
  unsigned short* wkb = (unsigned short*)(p + ((size_t)66 << 20));
  unsigned short* wvb = (unsigned short*)(p + ((size_t)68 << 20));
  unsigned short* opT = (unsigned short*)(p + ((size_t)96 << 20));  // [96,98M)

  dim3 blk(256);

  cvt_x<<<dim3(8192), blk, 0, stream>>>(x_f, xb);
  weight_prep<<<dim3(1024, 1, 4), blk, 0, stream>>>(wq_f, wk_f, wv_f, wo_f, wqb, wkb, wvb, opT);

  // fused QKV: M=8192, N=3*1024, K=1024
  gemm_qkv<<<dim3(24, 64), blk, 0, stream>>>(xb, wqb, wkb, wvb, QO, Kb, VT);

  // scores (all batches): [B][2048,2048] = Q @ K^T, causal skip
  gemm_bt<0, true, false><<<dim3(16, 16, 4), blk, 0, stream>>>(QO, Kb, SP, 1024, 1024, 2048, 1024,
      (long long)2048 * 1024, (long long)2048 * 1024, (long long)2048 * 2048);

  // P = causal_softmax(scores/32), in place, all batches
  softmax_causal<<<dim3(8192), blk, 0, stream>>>(SP);

  // O = P @ V (all batches), K limited to diagonal; O overwrites Q
  gemm_bt<0, false, true><<<dim3(8, 16, 4), blk, 0, stream>>>(SP, VT, QO, 2048, 2048, 1024, 2048,
      (long long)2048 * 2048, (long long)1024 * 2048, (long long)2048 * 1024);

  // out = O @ out_proj^T -> f32 d_out
  gemm_bt<1, false, false><<<dim3(8, 64, 1), blk, 0, stream>>>(QO, opT, out, 1024, 1024, 1024, 1024,
      0, 0, 0);
}